// Round 7
// baseline (1400.981 us; speedup 1.0000x reference)
//
#include <hip/hip_runtime.h>

// RNNSequenceEncoder: B=256, T=256, IN=128, H=1024
// Round-7: back to the PROVEN round-4 device-coherent (sc0 sc1) protocol.
// Rounds 5/6 proved sc0-only loads do NOT observe peer-CU stores within an
// XCD (poll deadlock x2) - XCD-local exchange abandoned.
// New in this round (structural, no new coherence semantics):
//  (1) MFMA operand swap: acc = mfma(W_frag, state_frag) -> transposed C/D:
//      each lane's 4 outputs = 4 CONSECUTIVE H-COLUMNS of one batch row ->
//      one packed 8B store per lane (512 stores/WG/step vs 2048 2B stores).
//  (2) x-prefetch for step t+2 issued between state stores and vmcnt(0),
//      hiding its latency under the store-ack round trip.
// Everything else identical to the 1257us round-4 kernel.

#define Bdim 256
#define Tdim 256
#define INdim 128
#define Hdim 1024

typedef __attribute__((ext_vector_type(8))) __bf16 bf16x8;
typedef __attribute__((ext_vector_type(4))) float f32x4;
typedef __attribute__((ext_vector_type(4))) int i32x4;
typedef __attribute__((ext_vector_type(2))) int i32x2;

#define OUT_BYTES ((size_t)Bdim * Tdim * Hdim * 4)   /* 256 MB */
#define SBYTES ((size_t)Bdim * Hdim * 2)             /* one bf16 state buffer: 512 KB */
#define CNT_BYTES 32768
#define SCRATCH_BYTES (CNT_BYTES + 2 * SBYTES)

// --- device-coherent ops (bypass L1+L2; visible device-wide; PROVEN) ---
static __device__ __forceinline__ void st_b64_c(void* p, i32x2 v) {
  asm volatile("global_store_dwordx2 %0, %1, off sc0 sc1" :: "v"(p), "v"(v) : "memory");
}
static __device__ __forceinline__ void st_b32_c(void* p, unsigned v) {
  asm volatile("global_store_dword %0, %1, off sc0 sc1" :: "v"(p), "v"(v) : "memory");
}
static __device__ __forceinline__ unsigned ld_b32_c(const void* p) {
  unsigned v;
  asm volatile("global_load_dword %0, %1, off sc0 sc1\n\ts_waitcnt vmcnt(0)"
               : "=v"(v) : "v"(p) : "memory");
  return v;
}
static __device__ __forceinline__ i32x4 ld_b128_c(const void* p) {
  i32x4 v;
  asm volatile("global_load_dwordx4 %0, %1, off sc0 sc1" : "=v"(v) : "v"(p) : "memory");
  return v;
}
static __device__ __forceinline__ void wait_vm0() {
  asm volatile("s_waitcnt vmcnt(0)" ::: "memory");
}

static __device__ __forceinline__ bf16x8 cvt8(f32x4 lo, f32x4 hi) {
  bf16x8 r;
  r[0] = (__bf16)lo[0]; r[1] = (__bf16)lo[1]; r[2] = (__bf16)lo[2]; r[3] = (__bf16)lo[3];
  r[4] = (__bf16)hi[0]; r[5] = (__bf16)hi[1]; r[6] = (__bf16)hi[2]; r[7] = (__bf16)hi[3];
  return r;
}

// pack two f32 -> one dword of 2 bf16 (lo first)
static __device__ __forceinline__ unsigned pk2(float a, float b) {
  unsigned sa = (unsigned)__builtin_bit_cast(unsigned short, (__bf16)a);
  unsigned sb = (unsigned)__builtin_bit_cast(unsigned short, (__bf16)b);
  return (sb << 16) | sa;
}

// Stage 16 rows x 1024 cols bf16 (32KB) coherence-point -> LDS, XOR swizzle on
// 16B chunks within each row (chunk ch lands at ch ^ (row&7)). 512 threads,
// 4 pipelined loads, one vmcnt(0), then LDS writes. (PROVEN round-4 code.)
static __device__ __forceinline__ void stage16c(const __bf16* __restrict__ src,
                                                __bf16* sA, int tid) {
  int r0 = (tid + 0) >> 7, c0 = (tid + 0) & 127;
  int r1 = (tid + 512) >> 7, c1 = (tid + 512) & 127;
  int r2 = (tid + 1024) >> 7, c2 = (tid + 1024) & 127;
  int r3 = (tid + 1536) >> 7, c3 = (tid + 1536) & 127;
  i32x4 v0 = ld_b128_c(src + (size_t)r0 * Hdim + c0 * 8);
  i32x4 v1 = ld_b128_c(src + (size_t)r1 * Hdim + c1 * 8);
  i32x4 v2 = ld_b128_c(src + (size_t)r2 * Hdim + c2 * 8);
  i32x4 v3 = ld_b128_c(src + (size_t)r3 * Hdim + c3 * 8);
  wait_vm0();
  *(i32x4*)(sA + (size_t)r0 * Hdim + ((c0 ^ (r0 & 7)) << 3)) = v0;
  *(i32x4*)(sA + (size_t)r1 * Hdim + ((c1 ^ (r1 & 7)) << 3)) = v1;
  *(i32x4*)(sA + (size_t)r2 * Hdim + ((c2 ^ (r2 & 7)) << 3)) = v2;
  *(i32x4*)(sA + (size_t)r3 * Hdim + ((c3 ^ (r3 & 7)) << 3)) = v3;
}

// state fragment from LDS: lane holds rows[lane&15][k0..k0+7], k0=kk*32+(lane>>4)*8,
// through the XOR swizzle. Used as the B-operand now (N-index = batch row).
static __device__ __forceinline__ bf16x8 afrag(const __bf16* sA, int lane, int kk) {
  int row = lane & 15;
  int ch = kk * 4 + (lane >> 4);
  return *(const bf16x8*)(sA + (size_t)row * Hdim + ((ch ^ (row & 7)) << 3));
}

__global__ void zero_cnt(unsigned* c) { c[blockIdx.x * 256 + threadIdx.x] = 0u; }

__global__ void __launch_bounds__(512, 1)
rnn_fused(const float* __restrict__ x, const float* __restrict__ W_in,
          const float* __restrict__ b_in, const float* __restrict__ W_rec,
          const float* __restrict__ b_rec, const float* __restrict__ W_out,
          const float* __restrict__ b_out, float* __restrict__ out,
          char* __restrict__ scratch) {
  __shared__ __align__(16) __bf16 sA[16 * Hdim];  // 32 KB

  unsigned* counters = (unsigned*)scratch;
  __bf16* buf0 = (__bf16*)(scratch + CNT_BYTES);
  __bf16* buf1 = buf0 + (size_t)Bdim * Hdim;

  int wg = blockIdx.x;               // 0..127
  int idx = wg >> 3;
  int r = (wg & 7) + 8 * (idx & 1);  // row block 0..15; its 8 WGs share wg&7
  int c = idx >> 1;                  // col chunk 0..7 (128 H cols)
  int tid = threadIdx.x;
  int lane = tid & 63;
  int ww = tid >> 6;                 // wave 0..7
  int kgrp = lane >> 4;

  int colw = c * 128 + ww * 16 + (lane & 15);  // weight-row this lane carries
  int colb = c * 128 + ww * 16 + kgrp * 4;     // first of 4 output cols (packed store)
  int grow = 16 * r + (lane & 15);             // batch row this lane owns (outputs + x)

  unsigned* rbf = counters + (size_t)r * 8 * 32;   // row-block flags, 128B apart
  unsigned* myflag = rbf + (size_t)c * 32;
  unsigned* gflags = counters + 4096;              // epilogue one-shot flags

  // --- preload weights (normal cached loads) ---
  // wrec[kk]: lane&15 -> W_rec row, lane>>4 -> k-group; identical fragment
  // structure for A- and B-operand use, so this is now the A-operand.
  bf16x8 wrec[32];
#pragma unroll
  for (int kk = 0; kk < 32; ++kk) {
    const float* p = W_rec + (size_t)colw * Hdim + kk * 32 + kgrp * 8;
    wrec[kk] = cvt8(*(const f32x4*)p, *(const f32x4*)(p + 4));
  }
  bf16x8 win[4];
#pragma unroll
  for (int kk = 0; kk < 4; ++kk) {
    const float* p = W_in + (size_t)colw * INdim + kk * 32 + kgrp * 8;
    win[kk] = cvt8(*(const f32x4*)p, *(const f32x4*)(p + 4));
  }
  f32x4 brec4 = *(const f32x4*)(b_rec + colb);
  f32x4 bin4 = *(const f32x4*)(b_in + colb);

  int xk0 = kgrp * 8;

  // --- phase 0: buf0 = version 1 = ext_0 ---
  // e = mfma(A=win, B=x rows): lane -> (batch row = lane&15, cols colb..colb+3)
  {
    f32x4 e = {0.f, 0.f, 0.f, 0.f};
#pragma unroll
    for (int kk = 0; kk < 4; ++kk) {
      const float* p = x + ((size_t)grow * Tdim + 0) * INdim + kk * 32 + xk0;
      e = __builtin_amdgcn_mfma_f32_16x16x32_bf16(
          win[kk], cvt8(*(const f32x4*)p, *(const f32x4*)(p + 4)), e, 0, 0, 0);
    }
    i32x2 w = {(int)pk2(e[0] + bin4[0], e[1] + bin4[1]),
               (int)pk2(e[2] + bin4[2], e[3] + bin4[3])};
    st_b64_c(buf0 + (size_t)grow * Hdim + colb, w);
  }
  wait_vm0();
  __syncthreads();
  if (tid == 0) st_b32_c(myflag, 1u);
  if (tid < 8) {
    unsigned* f = rbf + tid * 32;
    while (ld_b32_c(f) < 1u) __builtin_amdgcn_s_sleep(1);
  }
  __syncthreads();

  // prologue: prefetch x_1 (consumed by e-MFMA of step t=0)
  f32x4 xlo[4], xhi[4];
#pragma unroll
  for (int kk = 0; kk < 4; ++kk) {
    const float* p = x + ((size_t)grow * Tdim + 1) * INdim + kk * 32 + xk0;
    xlo[kk] = *(const f32x4*)p;
    xhi[kk] = *(const f32x4*)(p + 4);
  }

  // --- scan: 256 steps; version t+1 in buf[t&1]; xlo/xhi hold x_{t+1} ---
  const __bf16* cur = buf0;
  __bf16* nxt = buf1;
  for (int t = 0; t < Tdim; ++t) {
    stage16c(cur + (size_t)r * 16 * Hdim, sA, tid);
    __syncthreads();
    // acc = state @ W_rec^T, transposed into lanes:
    // lane -> (batch row = lane&15, out cols = colb..colb+3)
    f32x4 a0 = {0.f, 0.f, 0.f, 0.f}, a1 = a0, a2 = a0, a3 = a0;
#pragma unroll
    for (int kk = 0; kk < 32; kk += 4) {
      a0 = __builtin_amdgcn_mfma_f32_16x16x32_bf16(wrec[kk + 0], afrag(sA, lane, kk + 0), a0, 0, 0, 0);
      a1 = __builtin_amdgcn_mfma_f32_16x16x32_bf16(wrec[kk + 1], afrag(sA, lane, kk + 1), a1, 0, 0, 0);
      a2 = __builtin_amdgcn_mfma_f32_16x16x32_bf16(wrec[kk + 2], afrag(sA, lane, kk + 2), a2, 0, 0, 0);
      a3 = __builtin_amdgcn_mfma_f32_16x16x32_bf16(wrec[kk + 3], afrag(sA, lane, kk + 3), a3, 0, 0, 0);
    }
    f32x4 acc = (a0 + a1) + (a2 + a3);
    f32x4 e = {0.f, 0.f, 0.f, 0.f};
    if (t + 1 < Tdim) {
#pragma unroll
      for (int kk = 0; kk < 4; ++kk)
        e = __builtin_amdgcn_mfma_f32_16x16x32_bf16(win[kk], cvt8(xlo[kk], xhi[kk]), e, 0, 0, 0);
    }
    // v = relu(acc + b_rec) [+ ext_{t+1}]; one packed 8B coherent store/lane
    float v0, v1, v2, v3;
    {
      float s0 = acc[0] + brec4[0], s1 = acc[1] + brec4[1];
      float s2 = acc[2] + brec4[2], s3 = acc[3] + brec4[3];
      s0 = s0 > 0.f ? s0 : 0.f; s1 = s1 > 0.f ? s1 : 0.f;
      s2 = s2 > 0.f ? s2 : 0.f; s3 = s3 > 0.f ? s3 : 0.f;
      if (t + 1 < Tdim) {
        v0 = s0 + e[0] + bin4[0]; v1 = s1 + e[1] + bin4[1];
        v2 = s2 + e[2] + bin4[2]; v3 = s3 + e[3] + bin4[3];
      } else {
        v0 = s0; v1 = s1; v2 = s2; v3 = s3;
      }
    }
    i32x2 w = {(int)pk2(v0, v1), (int)pk2(v2, v3)};
    st_b64_c(nxt + (size_t)grow * Hdim + colb, w);
    // prefetch x_{t+2} NOW: its latency hides under the store-ack vmcnt(0)
    if (t + 2 < Tdim) {
#pragma unroll
      for (int kk = 0; kk < 4; ++kk) {
        const float* p = x + ((size_t)grow * Tdim + (t + 2)) * INdim + kk * 32 + xk0;
        xlo[kk] = *(const f32x4*)p;
        xhi[kk] = *(const f32x4*)(p + 4);
      }
    }
    // publish version t+2: own stores ack'd -> flag -> poll peers. Poll exit
    // at >= t+2 proves no peer still reads version t+1 (2-buffer safe).
    unsigned tgt = (unsigned)(t + 2);
    wait_vm0();
    __syncthreads();
    if (tid == 0) st_b32_c(myflag, tgt);
    if (tid < 8) {
      unsigned* f = rbf + tid * 32;
      while (ld_b32_c(f) < tgt) __builtin_amdgcn_s_sleep(1);
    }
    __syncthreads();
    const __bf16* tmp = cur; cur = nxt; nxt = (__bf16*)tmp;
  }

  // --- output: plop = state_257 @ W_out^T + b_out, broadcast over T ---
  // version 257 is in buf0 (cur == buf0 after 256 swaps)
  stage16c(buf0 + (size_t)r * 16 * Hdim, sA, tid);
  __syncthreads();
  // one-shot grid barrier (tail-scratch safety: nobody overwrites scratch
  // until everyone staged its state into LDS)
  if (tid == 0) st_b32_c(gflags + (size_t)wg * 16, 1u);
  if (tid < 128) {
    unsigned* f = gflags + (size_t)tid * 16;
    while (ld_b32_c(f) < 1u) __builtin_amdgcn_s_sleep(1);
  }
  __syncthreads();

  f32x4 a0 = {0.f, 0.f, 0.f, 0.f}, a1 = a0;
#pragma unroll
  for (int kk = 0; kk < 32; kk += 2) {
    const float* p0 = W_out + (size_t)colw * Hdim + (kk + 0) * 32 + kgrp * 8;
    const float* p1 = W_out + (size_t)colw * Hdim + (kk + 1) * 32 + kgrp * 8;
    a0 = __builtin_amdgcn_mfma_f32_16x16x32_bf16(
        cvt8(*(const f32x4*)p0, *(const f32x4*)(p0 + 4)), afrag(sA, lane, kk + 0), a0, 0, 0, 0);
    a1 = __builtin_amdgcn_mfma_f32_16x16x32_bf16(
        cvt8(*(const f32x4*)p1, *(const f32x4*)(p1 + 4)), afrag(sA, lane, kk + 1), a1, 0, 0, 0);
  }
  f32x4 acc = a0 + a1;
  f32x4 bo4 = *(const f32x4*)(b_out + colb);
  __syncthreads();  // afrag reads done before sA reuse
  float* sP = (float*)sA;  // 16 x 128 plop tile (f32, 8KB), [batch row][H col]
  *(f32x4*)(sP + (size_t)(lane & 15) * 128 + ww * 16 + kgrp * 4) = acc + bo4;
  __syncthreads();

  int h32 = tid & 31, tloc = tid >> 5;
  for (int b = 0; b < 16; ++b) {
    f32x4 v = *(const f32x4*)(sP + b * 128 + h32 * 4);
#pragma unroll
    for (int tb = 0; tb < 16; ++tb) {
      int t = tb * 16 + tloc;
      *(f32x4*)(out + ((size_t)(16 * r + b) * Tdim + t) * Hdim + 128 * c + h32 * 4) = v;
    }
  }
}

extern "C" void kernel_launch(void* const* d_in, const int* in_sizes, int n_in,
                              void* d_out, int out_size, void* d_ws, size_t ws_size,
                              hipStream_t stream) {
  const float* x = (const float*)d_in[0];
  const float* W_in = (const float*)d_in[1];
  const float* b_in = (const float*)d_in[2];
  const float* W_rec = (const float*)d_in[3];
  const float* b_rec = (const float*)d_in[4];
  const float* W_out = (const float*)d_in[5];
  const float* b_out = (const float*)d_in[6];
  float* out = (float*)d_out;
  (void)in_sizes; (void)n_in; (void)out_size;

  char* scratch = (ws_size >= SCRATCH_BYTES)
                      ? (char*)d_ws
                      : ((char*)d_out + OUT_BYTES - SCRATCH_BYTES);

  zero_cnt<<<dim3(CNT_BYTES / 1024), dim3(256), 0, stream>>>((unsigned*)scratch);
  rnn_fused<<<dim3(128), dim3(512), 0, stream>>>(x, W_in, b_in, W_rec, b_rec,
                                                 W_out, b_out, out, scratch);
}